// Round 7
// baseline (50.642 us; speedup 1.0000x reference)
//
#include <hip/hip_runtime.h>

#define H 384
#define W 384
#define C 19
#define NB 4
#define HP 382               // H - K + 1
#define HW (H * W)
#define CHW (C * HW)
#define TOTAL_TERMS 47279376.0f   // NB * 81 * HP*HP

#define TROWS 16
#define TCOLS 64
#define LROWS 18                  // TROWS + 2 halo rows
#define LSTRIDE 72                // floats per LDS row; slot s <-> float 4s (linear)
#define LBUF (LROWS * LSTRIDE)    // 1296 floats per buffer
#define NSLOTS (LBUF / 4)         // 324 float4 slots

// async global->LDS, 16B per lane, wave-uniform LDS base + lane*16
#define GLDS(gp, lp)                                                      \
    __builtin_amdgcn_global_load_lds(                                     \
        (const __attribute__((address_space(1))) void*)(gp),              \
        (__attribute__((address_space(3))) void*)(lp), 16, 0, 0)

// number of kernel-offsets a in [0,2] with 0 <= a+d <= 2 and 0 <= p-a <= HP-1
__device__ __forceinline__ int multv(int p, int d) {
    int lo = max(max(0, -d), p - (HP - 1));
    int hi = min(min(2, 2 - d), p);
    return max(0, hi - lo + 1);
}

__device__ __forceinline__ float bce_fast(float x, float y) {
    float t = __expf(-fabsf(x));
    return fmaxf(x, 0.0f) - x * y + __logf(1.0f + t);
}

// One block = 16x64-pixel tile, 256 threads, 4 px/thread.
// Per channel: async-stage the NEXT channel's (18x72)-float halo tile via
// global_load_lds while computing the current channel from LDS (9x
// ds_read_b128 per thread, 13 offset-dots). Double-buffered; the barrier's
// vmcnt drain is the staging completion wait (one full iteration of cover).
// Grid: 4 * 24 * 6 = 576 blocks, XCD-chunk swizzled.
__global__ __launch_bounds__(256) void affinity_partial(
        const float* __restrict__ logits,
        const int* __restrict__ labels,
        float* __restrict__ partial) {
    const int t    = threadIdx.x;
    const int tx   = t & 15;
    const int ty   = t >> 4;
    const int lane = t & 63;
    const int wid  = t >> 6;

    // XCD-aware remap: 576 tiles -> 8 chunks of 72 contiguous tiles
    const int b    = blockIdx.x;
    const int tile = (b & 7) * 72 + (b >> 3);
    const int n    = tile / 144;
    const int rem  = tile % 144;
    const int ty0  = (rem / 6) * TROWS;
    const int tx0  = (rem % 6) * TCOLS;

    // staging: slot s = (row s/18, f4col s%18); LDS float offset = 4s (linear).
    // wave w covers slots [64w,64w+64) and (waves 0,1) [256+64w, ...).
    // Clamped rows/cols only feed weight-0 terms (multv==0 outside image).
    const int s1 = wid * 64 + lane;                // < 256, always active
    const int s2 = 256 + wid * 64 + lane;          // active iff < 324
    const bool act2 = (s2 < NSLOTS);
    const int r1 = s1 / 18, j1 = s1 % 18;
    const int r2 = (act2 ? s2 : 0) / 18, j2 = (act2 ? s2 : 0) % 18;
    const int goff1 = min(ty0 + r1, H - 1) * W + min(max(tx0 - 4 + 4 * j1, 0), W - 4);
    const int goff2 = min(ty0 + r2, H - 1) * W + min(max(tx0 - 4 + 4 * j2, 0), W - 4);

    __shared__ __align__(16) float lds[2 * LBUF];   // 10368 B

    const float* srcb = logits + (size_t)n * CHW;

    // prologue: stage channel 0 into buffer 0
    {
        const float* src = srcb;
        float* buf = &lds[0];
        GLDS(src + goff1, buf + wid * 256);
        if (act2) GLDS(src + goff2, buf + 1024 + wid * 256);
    }
    __syncthreads();   // drains vmcnt -> channel 0 resident

    const int rbase = ty * LSTRIDE + 4 * tx;   // window cols px0-4 .. px0+7

    float acc[4][13];
#pragma unroll
    for (int i = 0; i < 4; ++i)
#pragma unroll
        for (int o = 0; o < 13; ++o) acc[i][o] = 0.0f;

    for (int c = 0; c < C; ++c) {
        const float* buf = &lds[(c & 1) * LBUF];

        // issue next channel's async stage FIRST (max latency cover)
        if (c + 1 < C) {
            const float* src = srcb + (size_t)(c + 1) * HW;
            float* nbuf = &lds[((c + 1) & 1) * LBUF];
            GLDS(src + goff1, nbuf + wid * 256);
            if (act2) GLDS(src + goff2, nbuf + 1024 + wid * 256);
        }

        float a[12], bb[12], e[12];
        *(float4*)&a[0]  = *(const float4*)&buf[rbase];
        *(float4*)&a[4]  = *(const float4*)&buf[rbase + 4];
        *(float4*)&a[8]  = *(const float4*)&buf[rbase + 8];
        *(float4*)&bb[0] = *(const float4*)&buf[rbase + LSTRIDE];
        *(float4*)&bb[4] = *(const float4*)&buf[rbase + LSTRIDE + 4];
        *(float4*)&bb[8] = *(const float4*)&buf[rbase + LSTRIDE + 8];
        *(float4*)&e[0]  = *(const float4*)&buf[rbase + 2 * LSTRIDE];
        *(float4*)&e[4]  = *(const float4*)&buf[rbase + 2 * LSTRIDE + 4];
        *(float4*)&e[8]  = *(const float4*)&buf[rbase + 2 * LSTRIDE + 8];

#pragma unroll
        for (int i = 0; i < 4; ++i) {
            const float s = a[4 + i];              // col px0+i
            acc[i][0] += s * s;                    // (0,0)
            acc[i][1] += s * a[5 + i];             // (0,1)
            acc[i][2] += s * a[6 + i];             // (0,2)
#pragma unroll
            for (int dxi = 0; dxi < 5; ++dxi) {
                acc[i][3 + dxi] += s * bb[2 + i + dxi];   // (1, dxi-2)
                acc[i][8 + dxi] += s * e[2 + i + dxi];    // (2, dxi-2)
            }
        }

        // barrier: all waves done reading buf, and (via its vmcnt drain)
        // next channel's stage is complete.
        __syncthreads();
    }

    // ---- epilogue: labels + weighted BCE ----
    const int py  = ty0 + ty;
    const int px0 = tx0 + 4 * tx;
    const int x0c = max(0, px0 - 4);
    const int d1  = px0 - x0c;
    const int d2  = min(W - 4, px0 + 4) - x0c;
    const int ro1 = (min(py + 1, H - 1) - py) * W;
    const int ro2 = (min(py + 2, H - 1) - py) * W;
    const int* lb0 = labels + (size_t)n * HW + (size_t)py * W + x0c;

    int la[12], lbr[12], ler[12];
    *(int4*)&la[0]  = *(const int4*)(lb0);
    *(int4*)&la[4]  = *(const int4*)(lb0 + d1);
    *(int4*)&la[8]  = *(const int4*)(lb0 + d2);
    *(int4*)&lbr[0] = *(const int4*)(lb0 + ro1);
    *(int4*)&lbr[4] = *(const int4*)(lb0 + ro1 + d1);
    *(int4*)&lbr[8] = *(const int4*)(lb0 + ro1 + d2);
    *(int4*)&ler[0] = *(const int4*)(lb0 + ro2);
    *(int4*)&ler[4] = *(const int4*)(lb0 + ro2 + d1);
    *(int4*)&ler[8] = *(const int4*)(lb0 + ro2 + d2);

    const int wy0 = multv(py, 0);
    const int wy1 = multv(py, 1);
    const int wy2 = multv(py, 2);

    float total = 0.0f;
#pragma unroll
    for (int i = 0; i < 4; ++i) {
        const int px = px0 + i;
        int wx[5];
#pragma unroll
        for (int dxi = 0; dxi < 5; ++dxi) wx[dxi] = multv(px, dxi - 2);
        const int ls = la[4 + i];

        total += (float)(wy0 * wx[2]) * bce_fast(acc[i][0], 1.0f);
        total += 2.0f * (float)(wy0 * wx[3]) *
                 bce_fast(acc[i][1], (ls == la[5 + i]) ? 1.0f : 0.0f);
        total += 2.0f * (float)(wy0 * wx[4]) *
                 bce_fast(acc[i][2], (ls == la[6 + i]) ? 1.0f : 0.0f);
#pragma unroll
        for (int dxi = 0; dxi < 5; ++dxi) {
            total += 2.0f * (float)(wy1 * wx[dxi]) *
                     bce_fast(acc[i][3 + dxi], (ls == lbr[2 + i + dxi]) ? 1.0f : 0.0f);
            total += 2.0f * (float)(wy2 * wx[dxi]) *
                     bce_fast(acc[i][8 + dxi], (ls == ler[2 + i + dxi]) ? 1.0f : 0.0f);
        }
    }

    // block reduction
#pragma unroll
    for (int off = 32; off > 0; off >>= 1) total += __shfl_down(total, off, 64);
    __shared__ float sm[4];
    if (lane == 0) sm[wid] = total;
    __syncthreads();
    if (t == 0)
        partial[blockIdx.x] = sm[0] + sm[1] + sm[2] + sm[3];
}

__global__ __launch_bounds__(256) void reduce_final(
        const float* __restrict__ partial, int n, float* __restrict__ out) {
    float s = 0.0f;
    for (int i = threadIdx.x; i < n; i += 256) s += partial[i];
#pragma unroll
    for (int off = 32; off > 0; off >>= 1) s += __shfl_down(s, off, 64);
    __shared__ float sm[4];
    const int lane = threadIdx.x & 63, wid = threadIdx.x >> 6;
    if (lane == 0) sm[wid] = s;
    __syncthreads();
    if (threadIdx.x == 0)
        out[0] = (sm[0] + sm[1] + sm[2] + sm[3]) / TOTAL_TERMS;
}

extern "C" void kernel_launch(void* const* d_in, const int* in_sizes, int n_in,
                              void* d_out, int out_size, void* d_ws, size_t ws_size,
                              hipStream_t stream) {
    const float* logits = (const float*)d_in[0];
    const int*   labels = (const int*)d_in[1];
    float* out     = (float*)d_out;
    float* partial = (float*)d_ws;   // 576 floats

    const int nblocks = NB * (H / TROWS) * (W / TCOLS);   // 576

    affinity_partial<<<nblocks, 256, 0, stream>>>(logits, labels, partial);
    reduce_final<<<1, 256, 0, stream>>>(partial, nblocks, out);
}